// Round 3
// baseline (1923.781 us; speedup 1.0000x reference)
//
#include <hip/hip_runtime.h>

typedef unsigned short u16;
typedef unsigned int u32;

#define N_USERS 100000
#define N_ITEMS 200000
#define N_NODES 300000
#define D 64
#define HYP 128
#define NNZ 4000000

// out is 96M fp32 elems: [user_out|item_out|gcn_hidden(2)|hgnn_hidden(2)]
constexpr long long SZL      = 19200000LL;        // one 300000x64 tensor
constexpr long long OUT_GCN0 = SZL;               // gcn_hidden base
constexpr long long OUT_HG0  = 3*SZL;             // hgnn_hidden base
// CSR col/val overlaid on hgnn[l=1] region [4*SZL,5*SZL): written only by the
// final two GEMMs, which launch after the last SpMM read of col/val.
constexpr long long OUT_COL  = 4*SZL;             // col_s: NNZ ints
constexpr long long OUT_VAL  = OUT_COL + NNZ;     // val_s: NNZ floats

typedef __attribute__((ext_vector_type(8))) short short8;
typedef __attribute__((ext_vector_type(4))) float f32x4;

__device__ __forceinline__ float bf2f(u16 u){ u32 i = ((u32)u) << 16; return __builtin_bit_cast(float, i); }
__device__ __forceinline__ u16 f2bf(float f){
  u32 i = __builtin_bit_cast(u32, f);
  return (u16)((i + 0x7FFFu + ((i >> 16) & 1u)) >> 16);
}

// emb (fp32) -> h_bf (bf16), hsum (fp32, == out[0:SZL)). 8 elems/thread.
__global__ void k_init(const float* __restrict__ ue, const float* __restrict__ ie,
                       u16* __restrict__ h_bf, float* __restrict__ hsum){
  int t = blockIdx.x*256 + threadIdx.x;
  int base = t*8;
  const float* src = (base < N_USERS*D) ? (ue + base) : (ie + (base - N_USERS*D));
  float4 v0 = *(const float4*)(src);
  float4 v1 = *(const float4*)(src + 4);
  *(float4*)(hsum + base)     = v0;
  *(float4*)(hsum + base + 4) = v1;
  uint4 p;
  p.x = (u32)f2bf(v0.x) | ((u32)f2bf(v0.y)<<16);
  p.y = (u32)f2bf(v0.z) | ((u32)f2bf(v0.w)<<16);
  p.z = (u32)f2bf(v1.x) | ((u32)f2bf(v1.y)<<16);
  p.w = (u32)f2bf(v1.z) | ((u32)f2bf(v1.w)<<16);
  *(uint4*)(h_bf + base) = p;
}

// C[M x N] = A[M x K] @ B[K x N]; A bf16 row-major, B fp32 staged in LDS as bf16,
// C fp32 (C32) or bf16. 32 rows/block, 4 waves.
template<int K, int N, bool C32>
__global__ __launch_bounds__(256) void k_gemm_tall(const u16* __restrict__ A,
                                                   const float* __restrict__ B,
                                                   void* __restrict__ Cv){
  constexpr int SROW = N + 2;                 // padded u16 stride (odd dword stride)
  __shared__ u32 blds[K*SROW/2];
  constexpr int PAIRS = K*N/2;
  for (int p = threadIdx.x; p < PAIRS; p += 256){
    int k = p/(N/2), c2 = p%(N/2);
    float f0 = B[2*p], f1 = B[2*p+1];
    blds[k*(SROW/2) + c2] = (u32)f2bf(f0) | ((u32)f2bf(f1)<<16);
  }
  __syncthreads();
  const u16* bl = (const u16*)blds;
  int wave = threadIdx.x>>6, lane = threadIdx.x&63, q = lane>>4, lm = lane&15;
  constexpr int NT = N/32;
  int mt = wave>>1, ntb = (wave&1)*NT;
  int r0 = blockIdx.x*32;
  f32x4 acc[NT];
  #pragma unroll
  for (int nt=0; nt<NT; ++nt) acc[nt] = (f32x4){0.f,0.f,0.f,0.f};
  const u16* arow = A + (size_t)(r0 + mt*16 + lm)*K + q*8;
  #pragma unroll
  for (int ks = 0; ks < K/32; ++ks){
    short8 a = *(const short8*)(arow + ks*32);
    #pragma unroll
    for (int nt = 0; nt < NT; ++nt){
      short8 b;
      #pragma unroll
      for (int j = 0; j < 8; ++j)
        b[j] = (short)bl[(ks*32 + q*8 + j)*SROW + (ntb+nt)*16 + lm];
      acc[nt] = __builtin_amdgcn_mfma_f32_16x16x32_bf16(a, b, acc[nt], 0, 0, 0);
    }
  }
  #pragma unroll
  for (int nt = 0; nt < NT; ++nt)
    #pragma unroll
    for (int r = 0; r < 4; ++r){
      int row = r0 + mt*16 + q*4 + r;       // C/D: col=lane&15, row=quad*4+reg (m89)
      int col = (ntb+nt)*16 + lm;
      if (C32) ((float*)Cv)[(size_t)row*N + col] = acc[nt][r];
      else     ((u16*)Cv)[(size_t)row*N + col] = f2bf(acc[nt][r]);
    }
}

// tmp[128x64] += Hyperᵀ[128 x rows] @ H[rows x 64] over a 512-row K-chunk per block.
__global__ __launch_bounds__(256) void k_step3(const u16* __restrict__ Hy,
                                               const u16* __restrict__ Hm,
                                               float* __restrict__ tmp, int rows){
  __shared__ u32 hyl[32*65];   // 32 k-rows x 128 elems, stride 130 u16
  __shared__ u32 hml[32*33];   // 32 k-rows x 64 elems,  stride 66 u16
  const u16* hyl16 = (const u16*)hyl;
  const u16* hml16 = (const u16*)hml;
  int tid = threadIdx.x;
  int wave = tid>>6, lane = tid&63, q = lane>>4, lm = lane&15;
  int k0 = blockIdx.x*512;
  f32x4 acc[2][4];
  #pragma unroll
  for (int i=0;i<2;i++)
    #pragma unroll
    for (int j=0;j<4;j++) acc[i][j] = (f32x4){0.f,0.f,0.f,0.f};
  for (int kk=0; kk<16; ++kk){
    int kb = k0 + kk*32;
    #pragma unroll
    for (int d0=0; d0<8; ++d0){
      int d = d0*256 + tid;
      int kr = d>>6, c2 = d&63, g = kb+kr;
      hyl[kr*65 + c2] = (g < rows) ? ((const u32*)Hy)[(size_t)g*64 + c2] : 0u;
    }
    #pragma unroll
    for (int d0=0; d0<4; ++d0){
      int d = d0*256 + tid;
      int kr = d>>5, c2 = d&31, g = kb+kr;
      hml[kr*33 + c2] = (g < rows) ? ((const u32*)Hm)[(size_t)g*32 + c2] : 0u;
    }
    __syncthreads();
    short8 a[2], b[4];
    #pragma unroll
    for (int ml=0; ml<2; ++ml)
      #pragma unroll
      for (int j=0;j<8;j++)
        a[ml][j] = (short)hyl16[(q*8+j)*130 + (wave*2+ml)*16 + lm];  // A[m][k]=Hy[k][m]
    #pragma unroll
    for (int nt=0; nt<4; ++nt)
      #pragma unroll
      for (int j=0;j<8;j++)
        b[nt][j] = (short)hml16[(q*8+j)*66 + nt*16 + lm];            // B[k][n]=Hm[k][n]
    #pragma unroll
    for (int ml=0; ml<2; ++ml)
      #pragma unroll
      for (int nt=0; nt<4; ++nt)
        acc[ml][nt] = __builtin_amdgcn_mfma_f32_16x16x32_bf16(a[ml], b[nt], acc[ml][nt], 0,0,0);
    __syncthreads();
  }
  #pragma unroll
  for (int ml=0; ml<2; ++ml)
    #pragma unroll
    for (int nt=0; nt<4; ++nt)
      #pragma unroll
      for (int r=0;r<4;r++){
        int m = (wave*2+ml)*16 + q*4 + r;
        int n = nt*16 + lm;
        atomicAdd(&tmp[m*64 + n], acc[ml][nt][r]);
      }
}

__global__ void k_hist(const int* __restrict__ rows_, int* __restrict__ cnt){
  int e = blockIdx.x*256 + threadIdx.x;
  if (e < NNZ){
    int r = rows_[e]; r = min(max(r,0), N_NODES-1);
    atomicAdd(&cnt[r], 1);
  }
}

__global__ __launch_bounds__(1024) void k_scan1(const int* __restrict__ cnt,
                                                int* __restrict__ rowptr, int* __restrict__ bsum){
  __shared__ int lds[1024];
  int i = blockIdx.x*1024 + threadIdx.x;
  int v = (i < N_NODES) ? cnt[i] : 0;
  lds[threadIdx.x] = v;
  for (int off=1; off<1024; off<<=1){
    __syncthreads();
    int add = (threadIdx.x >= off) ? lds[threadIdx.x-off] : 0;
    __syncthreads();
    lds[threadIdx.x] += add;
  }
  if (i < N_NODES) rowptr[i+1] = lds[threadIdx.x];
  if (threadIdx.x == 1023) bsum[blockIdx.x] = lds[1023];
}

__global__ __launch_bounds__(1024) void k_scan2(const int* __restrict__ bsum,
                                                int* __restrict__ boff, int nb){
  __shared__ int lds[1024];
  int t = threadIdx.x;
  int v = (t < nb) ? bsum[t] : 0;
  lds[t] = v;
  for (int off=1; off<1024; off<<=1){
    __syncthreads();
    int add = (t >= off) ? lds[t-off] : 0;
    __syncthreads();
    lds[t] += add;
  }
  if (t < nb) boff[t] = lds[t] - v;   // exclusive offsets
}

__global__ void k_scan3(const int* __restrict__ cnt, int* __restrict__ rowptr,
                        const int* __restrict__ boff, int* __restrict__ cursor){
  int i = blockIdx.x*256 + threadIdx.x;
  if (i == 0) rowptr[0] = 0;
  if (i < N_NODES){
    int inc = rowptr[i+1] + boff[i>>10];
    rowptr[i+1] = inc;
    cursor[i] = inc - cnt[i];
  }
}

__global__ void k_scatter(const int* __restrict__ rows_, const int* __restrict__ cols_,
                          const float* __restrict__ vals_, int* __restrict__ cursor,
                          int* __restrict__ col_s, float* __restrict__ val_s){
  int e = blockIdx.x*256 + threadIdx.x;
  if (e >= NNZ) return;
  int r = rows_[e]; r = min(max(r,0), N_NODES-1);
  int p = atomicAdd(&cursor[r], 1);
  p = min(max(p,0), NNZ-1);          // defensive: never write OOB
  col_s[p] = cols_[e];
  val_s[p] = vals_[e];
}

// One wave per row; cols/vals read coalesced, broadcast via shfl so gathers pipeline.
__global__ __launch_bounds__(256) void k_spmm(const int* __restrict__ rp,
                                              const int* __restrict__ cs,
                                              const float* __restrict__ vs,
                                              const u16* __restrict__ h,
                                              float* __restrict__ gout){
  int r = blockIdx.x*4 + (threadIdx.x>>6);
  int lane = threadIdx.x & 63;
  int beg = rp[r], end = rp[r+1];
  float acc = 0.f;
  for (int base = beg; base < end; base += 64){
    int c = 0; float v = 0.f;
    if (base + lane < end){ c = cs[base+lane]; v = vs[base+lane]; }
    int n = end - base; if (n > 64) n = 64;
    for (int e = 0; e < n; ++e){
      int ce = __shfl(c, e);
      float ve = __shfl(v, e);
      acc += ve * bf2f(h[(size_t)ce*64 + lane]);
    }
  }
  gout[(size_t)r*64 + lane] = acc;
}

// h = gcn + hg (fp32 in out); hsum += h (fp32 in out); h_bf = bf16(h)
__global__ void k_epilogue(const float* __restrict__ gcn, const float* __restrict__ hg,
                           float* __restrict__ hsum, u16* __restrict__ h_bf){
  int t = blockIdx.x*256 + threadIdx.x;
  int base = t*8;
  float hn[8], s[8];
  #pragma unroll
  for (int i0=0; i0<2; ++i0){
    float4 g4 = *(const float4*)(gcn + base + i0*4);
    float4 q4 = *(const float4*)(hg + base + i0*4);
    float4 s4 = *(const float4*)(hsum + base + i0*4);
    hn[i0*4+0] = g4.x + q4.x; s[i0*4+0] = s4.x + hn[i0*4+0];
    hn[i0*4+1] = g4.y + q4.y; s[i0*4+1] = s4.y + hn[i0*4+1];
    hn[i0*4+2] = g4.z + q4.z; s[i0*4+2] = s4.z + hn[i0*4+2];
    hn[i0*4+3] = g4.w + q4.w; s[i0*4+3] = s4.w + hn[i0*4+3];
  }
  *(float4*)(hsum + base)     = make_float4(s[0],s[1],s[2],s[3]);
  *(float4*)(hsum + base + 4) = make_float4(s[4],s[5],s[6],s[7]);
  uint4 p;
  p.x = (u32)f2bf(hn[0]) | ((u32)f2bf(hn[1])<<16);
  p.y = (u32)f2bf(hn[2]) | ((u32)f2bf(hn[3])<<16);
  p.z = (u32)f2bf(hn[4]) | ((u32)f2bf(hn[5])<<16);
  p.w = (u32)f2bf(hn[6]) | ((u32)f2bf(hn[7])<<16);
  *(uint4*)(h_bf + base) = p;
}

extern "C" void kernel_launch(void* const* d_in, const int* in_sizes, int n_in,
                              void* d_out, int out_size, void* d_ws, size_t ws_size,
                              hipStream_t stream) {
  const float* user_emb = (const float*)d_in[0];
  const float* item_emb = (const float*)d_in[1];
  const float* user_w   = (const float*)d_in[2];
  const float* item_w   = (const float*)d_in[3];
  const float* adj_vals = (const float*)d_in[4];
  const int* adj_rows = (const int*)d_in[5];
  const int* adj_cols = (const int*)d_in[6];
  float* out = (float*)d_out;

  // ws usage (≈119 MB): hyper 76.8M + h_bf 38.4M + CSR misc ~3.7M
  char* w = (char*)d_ws;
  auto alloc = [&](size_t b){ void* p = (void*)w; w += (b + 255) & ~(size_t)255; return p; };
  u16*   hyper = (u16*)  alloc((size_t)N_NODES*HYP*2);
  u16*   h_bf  = (u16*)  alloc((size_t)N_NODES*D*2);
  int*   cnt   = (int*)  alloc((size_t)N_NODES*4);
  int*   cursor= (int*)  alloc((size_t)N_NODES*4);
  int*   rowptr= (int*)  alloc((size_t)(N_NODES+1)*4);
  int*   bsum  = (int*)  alloc(1024*4);
  int*   boff  = (int*)  alloc(1024*4);
  float* tmp_u = (float*)alloc((size_t)HYP*D*4);
  float* tmp_i = (float*)alloc((size_t)HYP*D*4);   // adjacent to tmp_u

  // CSR col/val overlaid on out's hgnn[l=1] region (free until the last GEMMs)
  int*   col_s = (int*)  (out + OUT_COL);
  float* val_s = (float*)(out + OUT_VAL);
  float* hsum  = out;                              // fp32 hidden-sum accumulator

  hipMemsetAsync(cnt, 0, (size_t)N_NODES*4, stream);
  k_init<<<9375, 256, 0, stream>>>(user_emb, item_emb, h_bf, hsum);

  // hyper = bf16(emb) @ bf16(w)   (A = h_bf, built by k_init)
  k_gemm_tall<64,128,false><<<N_USERS/32, 256, 0, stream>>>(h_bf, user_w, hyper);
  k_gemm_tall<64,128,false><<<N_ITEMS/32, 256, 0, stream>>>(h_bf + (size_t)N_USERS*D, item_w,
                                                            hyper + (size_t)N_USERS*HYP);
  // CSR build (pattern reused by both layers)
  k_hist<<<(NNZ+255)/256, 256, 0, stream>>>(adj_rows, cnt);
  int nb1 = (N_NODES+1023)/1024;
  k_scan1<<<nb1, 1024, 0, stream>>>(cnt, rowptr, bsum);
  k_scan2<<<1, 1024, 0, stream>>>(bsum, boff, nb1);
  k_scan3<<<(N_NODES+255)/256, 256, 0, stream>>>(cnt, rowptr, boff, cursor);
  k_scatter<<<(NNZ+255)/256, 256, 0, stream>>>(adj_rows, adj_cols, adj_vals, cursor,
                                               col_s, val_s);

  for (int l = 0; l < 2; ++l){
    hipMemsetAsync(tmp_u, 0, (size_t)2*HYP*D*4, stream);  // zero tmp_u and tmp_i
    k_spmm<<<N_NODES/4, 256, 0, stream>>>(rowptr, col_s, val_s, h_bf,
                                          out + OUT_GCN0 + (size_t)l*SZL);
    k_step3<<<(N_USERS+511)/512, 256, 0, stream>>>(hyper, h_bf, tmp_u, N_USERS);
    k_step3<<<(N_ITEMS+511)/512, 256, 0, stream>>>(hyper + (size_t)N_USERS*HYP,
                                                   h_bf + (size_t)N_USERS*D, tmp_i, N_ITEMS);
    k_gemm_tall<128,64,true><<<N_USERS/32, 256, 0, stream>>>(hyper, tmp_u,
                                          out + OUT_HG0 + (size_t)l*SZL);
    k_gemm_tall<128,64,true><<<N_ITEMS/32, 256, 0, stream>>>(hyper + (size_t)N_USERS*HYP, tmp_i,
                                          out + OUT_HG0 + (size_t)l*SZL + (size_t)N_USERS*D);
    k_epilogue<<<9375, 256, 0, stream>>>(out + OUT_GCN0 + (size_t)l*SZL,
                                         out + OUT_HG0  + (size_t)l*SZL,
                                         hsum, h_bf);
  }
}